// Round 6
// baseline (16774.242 us; speedup 1.0000x reference)
//
#include <hip/hip_runtime.h>

#define BATCH 8
#define N 32768
#define NPOINT 2048
#define NT 512
#define NW 8
#define NC 32              // chunks of 1024 points
#define MARGIN 0.99999f    // conservative skip margin (>> 12-ulp f32 error)

typedef __attribute__((ext_vector_type(2))) float f2;
typedef unsigned long long u64;
typedef unsigned int u32;

__device__ __forceinline__ u32 spread5(u32 g) {
    return (g & 1u) | ((g & 2u) << 2) | ((g & 4u) << 4) |
           ((g & 8u) << 6) | ((g & 16u) << 8);
}

// 32 named f2 temp registers: T<ci><k>, ci=0..3 (chunk slot), k=0..7 (pair row)
#define REPCK(M) M(0,0) M(0,1) M(0,2) M(0,3) M(0,4) M(0,5) M(0,6) M(0,7) \
                 M(1,0) M(1,1) M(1,2) M(1,3) M(1,4) M(1,5) M(1,6) M(1,7) \
                 M(2,0) M(2,1) M(2,2) M(2,3) M(2,4) M(2,5) M(2,6) M(2,7) \
                 M(3,0) M(3,1) M(3,2) M(3,3) M(3,4) M(3,5) M(3,6) M(3,7)

__global__ __attribute__((amdgpu_flat_work_group_size(NT, NT)))
void fps_kernel(const float* __restrict__ pts_t,  // (B,3,N) original
                float* __restrict__ out,          // (B,3,NPOINT)
                float* __restrict__ ws)           // scratch: permuted coords
{
#pragma clang fp contract(off)
    __shared__ u32 s_key[N];          // 128 KiB: morton|oidx keys, then sorted
    __shared__ u64 s_kt[2][NC];       // per-chunk packed (maxtemp, argidx) keys
    __shared__ float s_boxf[NC * 6];  // chunk bboxes (also wave partials early)

    const int b = blockIdx.x;
    const int t = threadIdx.x;
    const int w = t >> 6;
    const int l = t & 63;

    const float* __restrict__ px = pts_t + (size_t)b * 3 * N;
    const float* __restrict__ py = px + N;
    const float* __restrict__ pz = py + N;
    float* __restrict__ Xw = ws + (size_t)b * 3 * N;
    float* __restrict__ Yw = Xw + N;
    float* __restrict__ Zw = Yw + N;
    const f2* __restrict__ X2 = (const f2*)Xw;
    const f2* __restrict__ Y2 = (const f2*)Yw;
    const f2* __restrict__ Z2 = (const f2*)Zw;
    float* outx = out + (size_t)b * 3 * NPOINT;
    float* outy = outx + NPOINT;
    float* outz = outy + NPOINT;

    // ================= Phase 0a: batch bbox =================
    float xl = 3.4e38f, xh = -3.4e38f, yl = 3.4e38f, yh = -3.4e38f,
          zl = 3.4e38f, zh = -3.4e38f;
    for (int i = 0; i < 64; ++i) {
        int p = i * NT + t;
        float vx = px[p], vy = py[p], vz = pz[p];
        xl = fminf(xl, vx); xh = fmaxf(xh, vx);
        yl = fminf(yl, vy); yh = fmaxf(yh, vy);
        zl = fminf(zl, vz); zh = fmaxf(zh, vz);
    }
#pragma unroll
    for (int o = 32; o >= 1; o >>= 1) {
        xl = fminf(xl, __shfl_xor(xl, o)); xh = fmaxf(xh, __shfl_xor(xh, o));
        yl = fminf(yl, __shfl_xor(yl, o)); yh = fmaxf(yh, __shfl_xor(yh, o));
        zl = fminf(zl, __shfl_xor(zl, o)); zh = fmaxf(zh, __shfl_xor(zh, o));
    }
    if (l == 0) {
        float* r = &s_boxf[w * 6];
        r[0] = xl; r[1] = xh; r[2] = yl; r[3] = yh; r[4] = zl; r[5] = zh;
    }
    __syncthreads();
    xl = 3.4e38f; xh = -3.4e38f; yl = 3.4e38f; yh = -3.4e38f;
    zl = 3.4e38f; zh = -3.4e38f;
#pragma unroll
    for (int ww = 0; ww < NW; ++ww) {
        const float* r = &s_boxf[ww * 6];
        xl = fminf(xl, r[0]); xh = fmaxf(xh, r[1]);
        yl = fminf(yl, r[2]); yh = fmaxf(yh, r[3]);
        zl = fminf(zl, r[4]); zh = fmaxf(zh, r[5]);
    }
    __syncthreads();

    // ================= Phase 0b: morton keys =================
    const float sx = 31.99f / fmaxf(xh - xl, 1e-30f);
    const float sy = 31.99f / fmaxf(yh - yl, 1e-30f);
    const float sz = 31.99f / fmaxf(zh - zl, 1e-30f);
    for (int i = 0; i < 64; ++i) {
        int p = i * NT + t;
        u32 gx = (u32)((px[p] - xl) * sx);
        u32 gy = (u32)((py[p] - yl) * sy);
        u32 gz = (u32)((pz[p] - zl) * sz);
        u32 cell = spread5(gx) | (spread5(gy) << 1) | (spread5(gz) << 2);
        s_key[p] = (cell << 15) | (u32)p;
    }
    __syncthreads();

    // ================= Phase 0c: bitonic sort (u32, LDS) =================
    for (u32 k2 = 2; k2 <= (u32)N; k2 <<= 1) {
        for (u32 jj = k2 >> 1; jj > 0; jj >>= 1) {
            for (int r = 0; r < 32; ++r) {
                u32 q = (u32)(r * NT + t);           // 0..16383
                u32 i = 2u * q - (q & (jj - 1u));
                u32 p2 = i | jj;
                bool up = ((i & k2) == 0u);
                u32 a = s_key[i], c = s_key[p2];
                u32 lo = a < c ? a : c, hi = a < c ? c : a;
                s_key[i]  = up ? lo : hi;
                s_key[p2] = up ? hi : lo;
            }
            __syncthreads();
        }
    }

    // ================= Phase 0d: permute coords into ws =================
    for (int i = 0; i < 64; ++i) {
        int s = i * NT + t;
        u32 o = s_key[s] & 32767u;
        Xw[s] = px[o]; Yw[s] = py[o]; Zw[s] = pz[o];
    }
    __threadfence();
    __syncthreads();

    // ============== Phase 0e: temps + chunk boxes + superbox ==============
#define DECLT(ci, k) f2 T##ci##k;
    REPCK(DECLT)
#undef DECLT
    float sbxl = 3.4e38f, sbxh = -3.4e38f, sbyl = 3.4e38f, sbyh = -3.4e38f,
          sbzl = 3.4e38f, sbzh = -3.4e38f;
    float ub0 = 1e10f, ub1 = 1e10f, ub2 = 1e10f, ub3 = 1e10f;

#define BOXP(ci, k) { u32 P = ((u32)(((ci) << 3) | w)) * 512u + (k) * 64u + (u32)l; \
        f2 Xv = X2[P], Yv = Y2[P], Zv = Z2[P];                                     \
        bxl = fminf(bxl, fminf(Xv.x, Xv.y)); bxh = fmaxf(bxh, fmaxf(Xv.x, Xv.y));  \
        byl = fminf(byl, fminf(Yv.x, Yv.y)); byh = fmaxf(byh, fmaxf(Yv.x, Yv.y));  \
        bzl = fminf(bzl, fminf(Zv.x, Zv.y)); bzh = fmaxf(bzh, fmaxf(Zv.x, Zv.y));  \
        T##ci##k = (f2){1e10f, 1e10f}; }
#define BOXC(ci) { float bxl = 3.4e38f, bxh = -3.4e38f, byl = 3.4e38f,             \
                   byh = -3.4e38f, bzl = 3.4e38f, bzh = -3.4e38f;                  \
        BOXP(ci,0) BOXP(ci,1) BOXP(ci,2) BOXP(ci,3)                                \
        BOXP(ci,4) BOXP(ci,5) BOXP(ci,6) BOXP(ci,7)                                \
        _Pragma("unroll")                                                          \
        for (int o = 32; o >= 1; o >>= 1) {                                        \
            bxl = fminf(bxl, __shfl_xor(bxl, o)); bxh = fmaxf(bxh, __shfl_xor(bxh, o)); \
            byl = fminf(byl, __shfl_xor(byl, o)); byh = fmaxf(byh, __shfl_xor(byh, o)); \
            bzl = fminf(bzl, __shfl_xor(bzl, o)); bzh = fmaxf(bzh, __shfl_xor(bzh, o)); \
        }                                                                          \
        if (l == 0) { float* r = &s_boxf[(((ci) << 3) | w) * 6];                   \
            r[0] = bxl; r[1] = bxh; r[2] = byl; r[3] = byh; r[4] = bzl; r[5] = bzh; } \
        sbxl = fminf(sbxl, bxl); sbxh = fmaxf(sbxh, bxh);                          \
        sbyl = fminf(sbyl, byl); sbyh = fmaxf(sbyh, byh);                          \
        sbzl = fminf(sbzl, bzl); sbzh = fmaxf(sbzh, bzh); }
    BOXC(0) BOXC(1) BOXC(2) BOXC(3)
#undef BOXC
#undef BOXP

    // First selected index is 0 (reference: idx[0] = 0).
    float lx = px[0], ly = py[0], lz = pz[0];
    if (t == 0) { outx[0] = lx; outy[0] = ly; outz[0] = lz; }
    __syncthreads();

    // ================= Main FPS loop =================
#define UPDP(ci, k) { u32 P = ((u32)(((ci) << 3) | w)) * 512u + (k) * 64u + (u32)l; \
        f2 Xv = X2[P], Yv = Y2[P], Zv = Z2[P];                                      \
        f2 dx = Xv - lx2, dy = Yv - ly2, dz = Zv - lz2;                             \
        f2 d2 = (dx * dx + dy * dy) + dz * dz;   /* numpy order, no fma */          \
        f2 tv = T##ci##k;                                                           \
        tv.x = fminf(tv.x, d2.x); tv.y = fminf(tv.y, d2.y);                         \
        T##ci##k = tv;                                                              \
        u32 o0 = s_key[2u * P] & 32767u, o1 = s_key[2u * P + 1u] & 32767u;          \
        u64 k0 = ((u64)__float_as_uint(tv.x) << 32) |                               \
                 (u64)(((32767u - o0) << 15) | (2u * P));                           \
        u64 k1 = ((u64)__float_as_uint(tv.y) << 32) |                               \
                 (u64)(((32767u - o1) << 15) | (2u * P + 1u));                      \
        bk = k0 > bk ? k0 : bk; bk = k1 > bk ? k1 : bk; }

#define CHUNK(ci, ubv) { const u32 c = ((ci) << 3) | (u32)w;                        \
        const float* r = &s_boxf[c * 6];                                            \
        float cx = fminf(fmaxf(lx, r[0]), r[1]);                                    \
        float cy = fminf(fmaxf(ly, r[2]), r[3]);                                    \
        float cz = fminf(fmaxf(lz, r[4]), r[5]);                                    \
        float mdx = lx - cx, mdy = ly - cy, mdz = lz - cz;                          \
        float m = (mdx * mdx + mdy * mdy) + mdz * mdz;                              \
        if (m * MARGIN >= ubv) {                                                    \
            if (l == 0) s_kt[jb][c] = s_kt[jo][c];                                  \
        } else {                                                                    \
            u64 bk = 0ull;                                                          \
            UPDP(ci,0) UPDP(ci,1) UPDP(ci,2) UPDP(ci,3)                             \
            UPDP(ci,4) UPDP(ci,5) UPDP(ci,6) UPDP(ci,7)                             \
            _Pragma("unroll")                                                       \
            for (int o = 32; o >= 1; o >>= 1) {                                     \
                u64 ok = __shfl_xor(bk, o); bk = ok > bk ? ok : bk;                 \
            }                                                                       \
            if (l == 0) s_kt[jb][c] = bk;                                           \
            ubv = __uint_as_float((u32)(bk >> 32));                                 \
        } }

    for (int j = 1; j < NPOINT; ++j) {
        const int jb = j & 1, jo = jb ^ 1;
        const f2 lx2 = (f2){lx, lx};
        const f2 ly2 = (f2){ly, ly};
        const f2 lz2 = (f2){lz, lz};

        // superbox early-out for the whole wave (4 chunks)
        float scx = fminf(fmaxf(lx, sbxl), sbxh);
        float scy = fminf(fmaxf(ly, sbyl), sbyh);
        float scz = fminf(fmaxf(lz, sbzl), sbzh);
        float sdx = lx - scx, sdy = ly - scy, sdz = lz - scz;
        float sm = (sdx * sdx + sdy * sdy) + sdz * sdz;
        float sub = fmaxf(fmaxf(ub0, ub1), fmaxf(ub2, ub3));
        if (sm * MARGIN >= sub) {
            if (l < 4) {
                u32 c = ((u32)l << 3) | (u32)w;
                s_kt[jb][c] = s_kt[jo][c];
            }
        } else {
            CHUNK(0, ub0) CHUNK(1, ub1) CHUNK(2, ub2) CHUNK(3, ub3)
        }
        __syncthreads();                       // the ONLY barrier

        // global argmax: 5-step butterfly over the 32 chunk keys
        u64 K = s_kt[jb][l & 31];
#pragma unroll
        for (int o = 16; o >= 1; o >>= 1) {
            u64 ok = __shfl_xor(K, o); K = ok > K ? ok : K;
        }
        u32 su = (u32)K & 32767u;
        su = (u32)__builtin_amdgcn_readfirstlane(su);
        lx = Xw[su]; ly = Yw[su]; lz = Zw[su];
        if (t == 0) { outx[j] = lx; outy[j] = ly; outz[j] = lz; }
    }
#undef CHUNK
#undef UPDP
}

extern "C" void kernel_launch(void* const* d_in, const int* in_sizes, int n_in,
                              void* d_out, int out_size, void* d_ws, size_t ws_size,
                              hipStream_t stream) {
    // d_in[0]: points_xyz (B,N,3) — unused
    // d_in[1]: points_xyz_t (B,3,N)
    // d_in[2]: features_with_xyz (B,67,N) — unused
    const float* pts_t = (const float*)d_in[1];
    float* out = (float*)d_out;
    fps_kernel<<<BATCH, NT, 0, stream>>>(pts_t, out, (float*)d_ws);
}

// Round 7
// 15326.311 us; speedup vs baseline: 1.0945x; 1.0945x over previous
//
#include <hip/hip_runtime.h>

#define BATCH 8
#define N 32768
#define NPOINT 2048
#define NT 512
#define NW 8
#define MARGIN 0.99999f    // conservative skip margin (>> accumulated ulp error)

typedef __attribute__((ext_vector_type(2))) float f2;
typedef __attribute__((ext_vector_type(2))) unsigned int u32x2;
typedef unsigned long long u64;
typedef unsigned int u32;

__device__ __forceinline__ u32 spread5(u32 g) {
    return (g & 1u) | ((g & 2u) << 2) | ((g & 4u) << 4) |
           ((g & 8u) << 6) | ((g & 16u) << 8);
}

__device__ __forceinline__ float rfl(float v) {
    return __uint_as_float((u32)__builtin_amdgcn_readfirstlane((int)__float_as_uint(v)));
}

// Wave-64 u64 max via DPP (gfx9 lineage): lane 63 ends with the wave max.
// Keys are < 2^63 and halves move together (bound_ctrl->0 = identity for max).
__device__ __forceinline__ u64 wave_max_u64(u64 v) {
#define DSTEP(ctrl, rmask) { \
    u32 lo = (u32)v, hi = (u32)(v >> 32); \
    u32 plo = (u32)__builtin_amdgcn_update_dpp(0, (int)lo, ctrl, rmask, 0xF, true); \
    u32 phi = (u32)__builtin_amdgcn_update_dpp(0, (int)hi, ctrl, rmask, 0xF, true); \
    u64 p = ((u64)phi << 32) | plo; \
    v = p > v ? p : v; }
    DSTEP(0x111, 0xF)  // row_shr:1
    DSTEP(0x112, 0xF)  // row_shr:2
    DSTEP(0x114, 0xF)  // row_shr:4
    DSTEP(0x118, 0xF)  // row_shr:8
    DSTEP(0x142, 0xA)  // row_bcast:15 -> rows 1,3
    DSTEP(0x143, 0xC)  // row_bcast:31 -> rows 2,3
#undef DSTEP
    return v;
}

// per-wave chunk slots ci=0..3, pair rows k=0..7
#define REP4(M) M(0) M(1) M(2) M(3)
#define REPCK(M) M(0,0) M(0,1) M(0,2) M(0,3) M(0,4) M(0,5) M(0,6) M(0,7) \
                 M(1,0) M(1,1) M(1,2) M(1,3) M(1,4) M(1,5) M(1,6) M(1,7) \
                 M(2,0) M(2,1) M(2,2) M(2,3) M(2,4) M(2,5) M(2,6) M(2,7) \
                 M(3,0) M(3,1) M(3,2) M(3,3) M(3,4) M(3,5) M(3,6) M(3,7)

__global__ __attribute__((amdgpu_flat_work_group_size(NT, NT)))
void fps_kernel(const float* __restrict__ pts_t,  // (B,3,N) original
                float* __restrict__ out,          // (B,3,NPOINT)
                float* __restrict__ ws)           // permuted coords (SoA)
{
#pragma clang fp contract(off)
    __shared__ u32 s_key[N];          // morton|oidx -> sorted -> packed (invo<<15|pos)
    __shared__ u64 s_red[2][NW];      // per-wave winner keys, double-buffered
    __shared__ float s_boxw[NW * 6];  // phase-0 wave partials

    const int b = blockIdx.x;
    const int t = threadIdx.x;
    const int w = t >> 6;
    const int l = t & 63;

    const float* __restrict__ px = pts_t + (size_t)b * 3 * N;
    const float* __restrict__ py = px + N;
    const float* __restrict__ pz = py + N;
    float* __restrict__ Xw = ws + (size_t)b * 3 * N;
    float* __restrict__ Yw = Xw + N;
    float* __restrict__ Zw = Yw + N;
    const f2* __restrict__ X2 = (const f2*)Xw;
    const f2* __restrict__ Y2 = (const f2*)Yw;
    const f2* __restrict__ Z2 = (const f2*)Zw;
    const u32x2* __restrict__ K2 = (const u32x2*)s_key;
    float* outx = out + (size_t)b * 3 * NPOINT;
    float* outy = outx + NPOINT;
    float* outz = outy + NPOINT;

    // ================= Phase 0a: batch bbox =================
    float xl = 3.4e38f, xh = -3.4e38f, yl = 3.4e38f, yh = -3.4e38f,
          zl = 3.4e38f, zh = -3.4e38f;
    for (int i = 0; i < 64; ++i) {
        int p = i * NT + t;
        float vx = px[p], vy = py[p], vz = pz[p];
        xl = fminf(xl, vx); xh = fmaxf(xh, vx);
        yl = fminf(yl, vy); yh = fmaxf(yh, vy);
        zl = fminf(zl, vz); zh = fmaxf(zh, vz);
    }
#pragma unroll
    for (int o = 32; o >= 1; o >>= 1) {
        xl = fminf(xl, __shfl_xor(xl, o)); xh = fmaxf(xh, __shfl_xor(xh, o));
        yl = fminf(yl, __shfl_xor(yl, o)); yh = fmaxf(yh, __shfl_xor(yh, o));
        zl = fminf(zl, __shfl_xor(zl, o)); zh = fmaxf(zh, __shfl_xor(zh, o));
    }
    if (l == 0) {
        float* r = &s_boxw[w * 6];
        r[0] = xl; r[1] = xh; r[2] = yl; r[3] = yh; r[4] = zl; r[5] = zh;
    }
    __syncthreads();
    xl = 3.4e38f; xh = -3.4e38f; yl = 3.4e38f; yh = -3.4e38f;
    zl = 3.4e38f; zh = -3.4e38f;
#pragma unroll
    for (int ww = 0; ww < NW; ++ww) {
        const float* r = &s_boxw[ww * 6];
        xl = fminf(xl, r[0]); xh = fmaxf(xh, r[1]);
        yl = fminf(yl, r[2]); yh = fmaxf(yh, r[3]);
        zl = fminf(zl, r[4]); zh = fmaxf(zh, r[5]);
    }
    __syncthreads();

    // ================= Phase 0b: morton keys =================
    const float sx = 31.99f / fmaxf(xh - xl, 1e-30f);
    const float sy = 31.99f / fmaxf(yh - yl, 1e-30f);
    const float sz = 31.99f / fmaxf(zh - zl, 1e-30f);
    for (int i = 0; i < 64; ++i) {
        int p = i * NT + t;
        u32 gx = (u32)((px[p] - xl) * sx);
        u32 gy = (u32)((py[p] - yl) * sy);
        u32 gz = (u32)((pz[p] - zl) * sz);
        u32 cell = spread5(gx) | (spread5(gy) << 1) | (spread5(gz) << 2);
        s_key[p] = (cell << 15) | (u32)p;
    }
    __syncthreads();

    // ================= Phase 0c: bitonic sort (u32, LDS) =================
    for (u32 k2 = 2; k2 <= (u32)N; k2 <<= 1) {
        for (u32 jj = k2 >> 1; jj > 0; jj >>= 1) {
            for (int r = 0; r < 32; ++r) {
                u32 q = (u32)(r * NT + t);
                u32 i = 2u * q - (q & (jj - 1u));
                u32 p2 = i | jj;
                bool up = ((i & k2) == 0u);
                u32 a = s_key[i], c = s_key[p2];
                u32 lo = a < c ? a : c, hi = a < c ? c : a;
                s_key[i]  = up ? lo : hi;
                s_key[p2] = up ? hi : lo;
            }
            __syncthreads();
        }
    }

    // ======= Phase 0d: permute coords into ws; repack keys to invo|pos =======
    for (int i = 0; i < 64; ++i) {
        int s = i * NT + t;
        u32 kk = s_key[s];
        u32 o = kk & 32767u;
        Xw[s] = px[o]; Yw[s] = py[o]; Zw[s] = pz[o];
        s_key[s] = ((32767u - o) << 15) | (u32)s;   // own-slot RMW, no race
    }
    __threadfence();
    __syncthreads();

    // ===== Phase 0e: temps + per-chunk bbox (-> SGPRs) + persistent keys =====
#define DECLT(ci, k) f2 T##ci##k;
    REPCK(DECLT)
#undef DECLT
#define DECLB(ci) float bxl##ci, bxh##ci, byl##ci, byh##ci, bzl##ci, bzh##ci; \
                  u64 ckey##ci;
    REP4(DECLB)
#undef DECLB

#define BOXP(ci, k) { u32 P = ((u32)(((ci) << 3) | w)) * 512u + (k) * 64u + (u32)l; \
        f2 Xv = X2[P], Yv = Y2[P], Zv = Z2[P];                                     \
        bxl = fminf(bxl, fminf(Xv.x, Xv.y)); bxh = fmaxf(bxh, fmaxf(Xv.x, Xv.y));  \
        byl = fminf(byl, fminf(Yv.x, Yv.y)); byh = fmaxf(byh, fmaxf(Yv.x, Yv.y));  \
        bzl = fminf(bzl, fminf(Zv.x, Zv.y)); bzh = fmaxf(bzh, fmaxf(Zv.x, Zv.y));  \
        T##ci##k = (f2){1e10f, 1e10f}; }
#define BOXC(ci) { float bxl = 3.4e38f, bxh = -3.4e38f, byl = 3.4e38f,             \
                   byh = -3.4e38f, bzl = 3.4e38f, bzh = -3.4e38f;                  \
        BOXP(ci,0) BOXP(ci,1) BOXP(ci,2) BOXP(ci,3)                                \
        BOXP(ci,4) BOXP(ci,5) BOXP(ci,6) BOXP(ci,7)                                \
        _Pragma("unroll")                                                          \
        for (int o = 32; o >= 1; o >>= 1) {                                        \
            bxl = fminf(bxl, __shfl_xor(bxl, o)); bxh = fmaxf(bxh, __shfl_xor(bxh, o)); \
            byl = fminf(byl, __shfl_xor(byl, o)); byh = fmaxf(byh, __shfl_xor(byh, o)); \
            bzl = fminf(bzl, __shfl_xor(bzl, o)); bzh = fmaxf(bzh, __shfl_xor(bzh, o)); \
        }                                                                          \
        bxl##ci = rfl(bxl); bxh##ci = rfl(bxh);                                    \
        byl##ci = rfl(byl); byh##ci = rfl(byh);                                    \
        bzl##ci = rfl(bzl); bzh##ci = rfl(bzh);                                    \
        ckey##ci = ((u64)__float_as_uint(1e10f) << 32); }
    REP4(BOXC)
#undef BOXC
#undef BOXP

    // First selected index is 0 (reference: idx[0] = 0).
    float lx = px[0], ly = py[0], lz = pz[0];
    if (t == 0) { outx[0] = lx; outy[0] = ly; outz[0] = lz; }
    __syncthreads();

    // ================= Main FPS loop =================
#define UPDP(ci, k) { const u32 P = cb + (k) * 64u + (u32)l;                  \
        f2 Xv = X2[P], Yv = Y2[P], Zv = Z2[P];                                \
        u32x2 pk = K2[P];                      /* one ds_read_b64 */          \
        f2 dx = Xv - lx2, dy = Yv - ly2, dz = Zv - lz2;                       \
        f2 d2 = (dx * dx + dy * dy) + dz * dz; /* numpy order, no fma */      \
        f2 tv = T##ci##k;                                                     \
        tv.x = fminf(tv.x, d2.x); tv.y = fminf(tv.y, d2.y);                   \
        T##ci##k = tv;                                                        \
        u64 k0 = ((u64)__float_as_uint(tv.x) << 32) | pk.x;                   \
        u64 k1 = ((u64)__float_as_uint(tv.y) << 32) | pk.y;                   \
        bk = k0 > bk ? k0 : bk; bk = k1 > bk ? k1 : bk; }

#define CHUNK(ci) {                                                           \
        float cx = fminf(fmaxf(lx, bxl##ci), bxh##ci);                        \
        float cy = fminf(fmaxf(ly, byl##ci), byh##ci);                        \
        float cz = fminf(fmaxf(lz, bzl##ci), bzh##ci);                        \
        float mdx = lx - cx, mdy = ly - cy, mdz = lz - cz;                    \
        float m = (mdx * mdx + mdy * mdy) + mdz * mdz;                        \
        float ub = __uint_as_float((u32)(ckey##ci >> 32));                    \
        if (__any(m * MARGIN < ub)) {          /* wave-uniform vcc branch */  \
            const u32 cb = ((u32)(((ci) << 3) | w)) * 512u;                   \
            u64 bk = 0ull;                                                    \
            UPDP(ci,0) UPDP(ci,1) UPDP(ci,2) UPDP(ci,3)                       \
            UPDP(ci,4) UPDP(ci,5) UPDP(ci,6) UPDP(ci,7)                       \
            ckey##ci = bk;                                                    \
        } }

    for (int j = 1; j < NPOINT; ++j) {
        const int jb = j & 1;
        const f2 lx2 = (f2){lx, lx};
        const f2 ly2 = (f2){ly, ly};
        const f2 lz2 = (f2){lz, lz};

        REP4(CHUNK)

        // per-lane best over the wave's 4 chunks, then DPP wave max
        u64 K = ckey0;
        K = ckey1 > K ? ckey1 : K;
        K = ckey2 > K ? ckey2 : K;
        K = ckey3 > K ? ckey3 : K;
        K = wave_max_u64(K);
        if (l == 63) s_red[jb][w] = K;
        __syncthreads();                       // the ONLY barrier

        // redundant 8-way reduce (LDS broadcast reads)
        u64 KK = s_red[jb][0];
#pragma unroll
        for (int ww = 1; ww < NW; ++ww) {
            u64 o = s_red[jb][ww];
            KK = o > KK ? o : KK;
        }
        u32 su = (u32)KK & 32767u;             // sorted position of winner
        su = (u32)__builtin_amdgcn_readfirstlane((int)su);
        lx = Xw[su]; ly = Yw[su]; lz = Zw[su];
        if (t == 0) { outx[j] = lx; outy[j] = ly; outz[j] = lz; }
    }
#undef CHUNK
#undef UPDP
}

extern "C" void kernel_launch(void* const* d_in, const int* in_sizes, int n_in,
                              void* d_out, int out_size, void* d_ws, size_t ws_size,
                              hipStream_t stream) {
    // d_in[0]: points_xyz (B,N,3) — unused
    // d_in[1]: points_xyz_t (B,3,N)
    // d_in[2]: features_with_xyz (B,67,N) — unused
    const float* pts_t = (const float*)d_in[1];
    float* out = (float*)d_out;
    fps_kernel<<<BATCH, NT, 0, stream>>>(pts_t, out, (float*)d_ws);
}

// Round 8
// 5992.340 us; speedup vs baseline: 2.7993x; 2.5577x over previous
//
#include <hip/hip_runtime.h>

#define BATCH 8
#define N 32768
#define NPOINT 2048
#define NT 512
#define NW 8
#define MARGIN 0.99999f    // conservative skip margin (>> accumulated ulp error)

typedef __attribute__((ext_vector_type(2))) float f2;
typedef unsigned long long u64;
typedef unsigned int u32;
typedef unsigned short u16;

__device__ __forceinline__ u32 spread5(u32 g) {
    return (g & 1u) | ((g & 2u) << 2) | ((g & 4u) << 4) |
           ((g & 8u) << 6) | ((g & 16u) << 8);
}

// Wave-64 u64 max via DPP: lane 63 ends with the wave max (r7-verified).
__device__ __forceinline__ u64 wave_max_u64(u64 v) {
#define DSTEP(ctrl, rmask) { \
    u32 lo = (u32)v, hi = (u32)(v >> 32); \
    u32 plo = (u32)__builtin_amdgcn_update_dpp(0, (int)lo, ctrl, rmask, 0xF, true); \
    u32 phi = (u32)__builtin_amdgcn_update_dpp(0, (int)hi, ctrl, rmask, 0xF, true); \
    u64 p = ((u64)phi << 32) | plo; \
    v = p > v ? p : v; }
    DSTEP(0x111, 0xF)  // row_shr:1
    DSTEP(0x112, 0xF)  // row_shr:2
    DSTEP(0x114, 0xF)  // row_shr:4
    DSTEP(0x118, 0xF)  // row_shr:8
    DSTEP(0x142, 0xA)  // row_bcast:15 -> rows 1,3
    DSTEP(0x143, 0xC)  // row_bcast:31 -> rows 2,3
#undef DSTEP
    return v;
}

#define REP32(M)  M(0)  M(1)  M(2)  M(3)  M(4)  M(5)  M(6)  M(7)  \
                  M(8)  M(9)  M(10) M(11) M(12) M(13) M(14) M(15) \
                  M(16) M(17) M(18) M(19) M(20) M(21) M(22) M(23) \
                  M(24) M(25) M(26) M(27) M(28) M(29) M(30) M(31)

// One block per batch. Morton-sort once, then:
//   x,y     : 64 named f2 vars (unified VGPR/AGPR file — r3-proven residency)
//   z       : LDS (128 KiB, reusing the sort-key buffer)
//   temps T : 32 named f2 register vars
//   chunks  : 32 per wave (128 sorted pts each), bboxes in LDS SoA
// Per iter: lane-parallel chunk bbox tests vs the wave's exact max temp
// (ballot -> mask), statically-unrolled bodies under wave-uniform branches,
// full register-only rescan for the wave key, DPP u64 butterfly, ONE barrier.
// Skip is bit-exact: skipped chunk => computed d2 >= temp for every point.
// Bit-exact numpy semantics: contract off, (xx+yy)+zz, oidx tie-break in key.
__global__ __attribute__((amdgpu_flat_work_group_size(NT, NT),
                          amdgpu_waves_per_eu(2, 2)))
void fps_kernel(const float* __restrict__ pts_t,  // (B,3,N) original
                float* __restrict__ out,          // (B,3,NPOINT)
                float* __restrict__ ws)           // X,Y,Z f32 + IV u16 per batch
{
#pragma clang fp contract(off)
    __shared__ __align__(16) u32 s_key[N];   // sort keys, then z as f32
    __shared__ u64 s_red[2][NW];             // per-wave keys, double-buffered
    __shared__ float s_bxl[256], s_bxh[256], s_byl[256], s_byh[256],
                     s_bzl[256], s_bzh[256]; // chunk bboxes (SoA, 6 KiB)

    const int b = blockIdx.x;
    const int t = threadIdx.x;
    const int w = t >> 6;
    const int l = t & 63;

    const float* __restrict__ px = pts_t + (size_t)b * 3 * N;
    const float* __restrict__ py = px + N;
    const float* __restrict__ pz = py + N;
    float* __restrict__ Xw = ws + (size_t)b * 3 * N;
    float* __restrict__ Yw = Xw + N;
    float* __restrict__ Zw = Yw + N;
    u16* __restrict__ IVp = (u16*)(ws + (size_t)BATCH * 3 * N) + (size_t)b * N;
    const f2* __restrict__ X2 = (const f2*)Xw;
    const f2* __restrict__ Y2 = (const f2*)Yw;
    const f2* __restrict__ s_z2 = (const f2*)s_key;
    float* __restrict__ s_zf = (float*)s_key;
    float* outx = out + (size_t)b * 3 * NPOINT;
    float* outy = outx + NPOINT;
    float* outz = outy + NPOINT;

    // ================= Phase 0a: batch bbox =================
    float xl = 3.4e38f, xh = -3.4e38f, yl = 3.4e38f, yh = -3.4e38f,
          zl = 3.4e38f, zh = -3.4e38f;
    for (int i = 0; i < 64; ++i) {
        int p = i * NT + t;
        float vx = px[p], vy = py[p], vz = pz[p];
        xl = fminf(xl, vx); xh = fmaxf(xh, vx);
        yl = fminf(yl, vy); yh = fmaxf(yh, vy);
        zl = fminf(zl, vz); zh = fmaxf(zh, vz);
    }
#pragma unroll
    for (int o = 32; o >= 1; o >>= 1) {
        xl = fminf(xl, __shfl_xor(xl, o)); xh = fmaxf(xh, __shfl_xor(xh, o));
        yl = fminf(yl, __shfl_xor(yl, o)); yh = fmaxf(yh, __shfl_xor(yh, o));
        zl = fminf(zl, __shfl_xor(zl, o)); zh = fmaxf(zh, __shfl_xor(zh, o));
    }
    if (l == 0) {
        s_bxl[w] = xl; s_bxh[w] = xh; s_byl[w] = yl; s_byh[w] = yh;
        s_bzl[w] = zl; s_bzh[w] = zh;
    }
    __syncthreads();
    xl = 3.4e38f; xh = -3.4e38f; yl = 3.4e38f; yh = -3.4e38f;
    zl = 3.4e38f; zh = -3.4e38f;
#pragma unroll
    for (int ww = 0; ww < NW; ++ww) {
        xl = fminf(xl, s_bxl[ww]); xh = fmaxf(xh, s_bxh[ww]);
        yl = fminf(yl, s_byl[ww]); yh = fmaxf(yh, s_byh[ww]);
        zl = fminf(zl, s_bzl[ww]); zh = fmaxf(zh, s_bzh[ww]);
    }
    __syncthreads();

    // ================= Phase 0b: morton keys =================
    const float sxm = 31.99f / fmaxf(xh - xl, 1e-30f);
    const float sym = 31.99f / fmaxf(yh - yl, 1e-30f);
    const float szm = 31.99f / fmaxf(zh - zl, 1e-30f);
    for (int i = 0; i < 64; ++i) {
        int p = i * NT + t;
        u32 gx = (u32)((px[p] - xl) * sxm);
        u32 gy = (u32)((py[p] - yl) * sym);
        u32 gz = (u32)((pz[p] - zl) * szm);
        u32 cell = spread5(gx) | (spread5(gy) << 1) | (spread5(gz) << 2);
        s_key[p] = (cell << 15) | (u32)p;
    }
    __syncthreads();

    // ================= Phase 0c: bitonic sort (u32, LDS) =================
    for (u32 k2 = 2; k2 <= (u32)N; k2 <<= 1) {
        for (u32 jj = k2 >> 1; jj > 0; jj >>= 1) {
            for (int r = 0; r < 32; ++r) {
                u32 q = (u32)(r * NT + t);
                u32 i = 2u * q - (q & (jj - 1u));
                u32 p2 = i | jj;
                bool up = ((i & k2) == 0u);
                u32 a = s_key[i], c = s_key[p2];
                u32 lo = a < c ? a : c, hi = a < c ? c : a;
                s_key[i]  = up ? lo : hi;
                s_key[p2] = up ? hi : lo;
            }
            __syncthreads();
        }
    }

    // ===== Phase 0d: permute coords + inv-oidx into ws; z into LDS =====
    for (int i = 0; i < 64; ++i) {
        int s = i * NT + t;
        u32 o = s_key[s] & 32767u;
        Xw[s] = px[o]; Yw[s] = py[o]; Zw[s] = pz[o];
        IVp[s] = (u16)(32767u - o);
    }
    __threadfence();
    __syncthreads();
    for (int i = 0; i < 64; ++i) {           // overwrite keys with z (f32)
        int s = i * NT + t;
        s_zf[s] = Zw[s];
    }

    // ---- load x,y into registers (wave-contiguous: q = w*2048 + k*64 + l) ----
#define DECL(k) f2 x##k, y##k, T##k;
    REP32(DECL)
#undef DECL
    const int qbase = w * 2048 + l;
#define LOADXY(k) { x##k = X2[qbase + (k) * 64]; y##k = Y2[qbase + (k) * 64]; }
    REP32(LOADXY)
#undef LOADXY
    __syncthreads();                         // all z writes visible

    // ===== Phase 0e: per-chunk bboxes (from regs + LDS z) + temp init =====
#define BOXK(k) { f2 zv = s_z2[qbase + (k) * 64];                              \
        float bxl = fminf(x##k.x, x##k.y), bxh = fmaxf(x##k.x, x##k.y);        \
        float byl = fminf(y##k.x, y##k.y), byh = fmaxf(y##k.x, y##k.y);        \
        float bzl = fminf(zv.x, zv.y),     bzh = fmaxf(zv.x, zv.y);            \
        _Pragma("unroll")                                                      \
        for (int o = 32; o >= 1; o >>= 1) {                                    \
            bxl = fminf(bxl, __shfl_xor(bxl, o)); bxh = fmaxf(bxh, __shfl_xor(bxh, o)); \
            byl = fminf(byl, __shfl_xor(byl, o)); byh = fmaxf(byh, __shfl_xor(byh, o)); \
            bzl = fminf(bzl, __shfl_xor(bzl, o)); bzh = fmaxf(bzh, __shfl_xor(bzh, o)); \
        }                                                                      \
        if (l == 0) { int c = (w << 5) | (k);                                  \
            s_bxl[c] = bxl; s_bxh[c] = bxh; s_byl[c] = byl; s_byh[c] = byh;    \
            s_bzl[c] = bzl; s_bzh[c] = bzh; }                                  \
        T##k = (f2){1e10f, 1e10f}; }
    REP32(BOXK)
#undef BOXK
    if (l == 63) {
        s_red[0][w] = ((u64)__float_as_uint(1e10f) << 32);
        s_red[1][w] = ((u64)__float_as_uint(1e10f) << 32);
    }

    // First selected index is 0 (reference: idx[0] = 0).
    float lx = px[0], ly = py[0], lz = pz[0];
    if (t == 0) { outx[0] = lx; outy[0] = ly; outz[0] = lz; }
    __syncthreads();

    // ================= Main FPS loop =================
#define BODY(k) if (mask & (1u << (k))) {                                      \
        f2 zv = s_z2[qbase + (k) * 64];                                        \
        f2 dx = x##k - lx2, dy = y##k - ly2, dz = zv - lz2;                    \
        f2 d2 = (dx * dx + dy * dy) + dz * dz;  /* numpy order, no fma */      \
        T##k.x = fminf(T##k.x, d2.x);                                          \
        T##k.y = fminf(T##k.y, d2.y); }

#define SCAN(k) { float fm = fmaxf(T##k.x, T##k.y);                            \
        int p0 = pbase + (k) * 128;                                            \
        int pk = (T##k.y > T##k.x) ? p0 + 1 : p0;                              \
        bestpos = (fm > bestf) ? pk : bestpos;                                 \
        bestf = fmaxf(bestf, fm); }

    const int pbase = w * 4096 + 2 * l;
    for (int j = 1; j < NPOINT; ++j) {
        const int jb = j & 1, jo = jb ^ 1;
        u64 wkey = s_red[jo][w];               // wave's exact max key (stale ok)
        float ub = __uint_as_float((u32)(wkey >> 32));
        const f2 lx2 = (f2){lx, lx};
        const f2 ly2 = (f2){ly, ly};
        const f2 lz2 = (f2){lz, lz};

        // lane-parallel chunk bbox tests (lanes 0..31 each test one chunk)
        int cc = (w << 5) | (l & 31);
        float cx = fminf(fmaxf(lx, s_bxl[cc]), s_bxh[cc]);
        float cy = fminf(fmaxf(ly, s_byl[cc]), s_byh[cc]);
        float cz = fminf(fmaxf(lz, s_bzl[cc]), s_bzh[cc]);
        float mdx = lx - cx, mdy = ly - cy, mdz = lz - cz;
        float m = (mdx * mdx + mdy * mdy) + mdz * mdz;
        bool proc = (l < 32) && (m * MARGIN < ub);
        u32 mask = (u32)__ballot(proc);
        mask = (u32)__builtin_amdgcn_readfirstlane((int)mask);

        if (mask) {
            REP32(BODY)                        // update processed chunks only
            float bestf = -1.0f; int bestpos = 0;
            REP32(SCAN)                        // full register rescan -> exact
            u16 iv = IVp[bestpos];             // inv original idx (tie-break)
            u64 key = ((u64)__float_as_uint(bestf) << 32) |
                      ((u64)iv << 15) | (u64)(u32)bestpos;
            key = wave_max_u64(key);
            if (l == 63) s_red[jb][w] = key;
        } else {
            if (l == 63) s_red[jb][w] = wkey;  // nothing changed: carry key
        }
        __syncthreads();                       // the ONLY barrier

        // redundant 8-way reduce (LDS broadcast reads)
        u64 KK = s_red[jb][0];
#pragma unroll
        for (int ww = 1; ww < NW; ++ww) {
            u64 o = s_red[jb][ww];
            KK = o > KK ? o : KK;
        }
        u32 sel = (u32)KK & 32767u;            // sorted position of winner
        sel = (u32)__builtin_amdgcn_readfirstlane((int)sel);
        lx = Xw[sel]; ly = Yw[sel]; lz = Zw[sel];
        if (t == 0) { outx[j] = lx; outy[j] = ly; outz[j] = lz; }
    }
#undef BODY
#undef SCAN
}

extern "C" void kernel_launch(void* const* d_in, const int* in_sizes, int n_in,
                              void* d_out, int out_size, void* d_ws, size_t ws_size,
                              hipStream_t stream) {
    // d_in[0]: points_xyz (B,N,3) — unused
    // d_in[1]: points_xyz_t (B,3,N)
    // d_in[2]: features_with_xyz (B,67,N) — unused
    // ws: [B][3][N] f32 sorted coords + [B][N] u16 inv-oidx  (3.5 MB)
    const float* pts_t = (const float*)d_in[1];
    float* out = (float*)d_out;
    fps_kernel<<<BATCH, NT, 0, stream>>>(pts_t, out, (float*)d_ws);
}